// Round 2
// baseline (8803.161 us; speedup 1.0000x reference)
//
#include <hip/hip_runtime.h>
#include <hip/hip_bf16.h>

#define BB   128
#define SS   256
#define DD   512
#define HH   1024
#define NCC  128
#define NCLS 129
#define G4   4096   // 4*HH, gate-interleaved: j = hcol*4 + gate (f,i,g,o)
#define NWG  256    // persistent grid size

typedef __attribute__((ext_vector_type(8)))  short  short8;
typedef __attribute__((ext_vector_type(4)))  float  f32x4;
typedef __attribute__((ext_vector_type(16))) float  f32x16;

static __device__ __forceinline__ float sigm(float x)  { return 1.0f / (1.0f + __expf(-x)); }
static __device__ __forceinline__ float tanh_(float x) { return 1.0f - 2.0f / (__expf(2.0f * x) + 1.0f); }
static __device__ __forceinline__ unsigned short f2b(float v) {
    __hip_bfloat16 h = __float2bfloat16(v);
    return *reinterpret_cast<unsigned short*>(&h);
}
static __device__ __forceinline__ short8 ld16(const unsigned short* p) {
    return *reinterpret_cast<const short8*>(p);
}

// ---------------- zero-init h buffer 0 and barrier counters ----------------
__global__ void k_init(unsigned short* __restrict__ hb0, int* __restrict__ bar) {
    int i = blockIdx.x * 256 + threadIdx.x;
    if (i < BB * HH) hb0[i] = 0;
    if (i < SS) bar[i] = 0;
}

// ---------------- Wh -> bf16, transposed, gate-interleaved ----------------
// WhT[j][k] = W{gate}h[k][hcol], j = hcol*4 + gate.  LDS-tiled transpose.
__global__ void k_conv_wh(const float* __restrict__ Wfh, const float* __restrict__ Wih,
                          const float* __restrict__ Wgh, const float* __restrict__ Woh,
                          unsigned short* __restrict__ WhT) {
    __shared__ float t[32][33];
    int g = blockIdx.z;
    const float* W = (g == 0) ? Wfh : (g == 1) ? Wih : (g == 2) ? Wgh : Woh;
    int h0 = blockIdx.x * 32, k0 = blockIdx.y * 32;
    int tx = threadIdx.x & 31, ty = threadIdx.x >> 5;   // ty in 0..7
    for (int r = 0; r < 4; r++) {
        int k = ty + r * 8;
        t[k][tx] = W[(size_t)(k0 + k) * HH + h0 + tx];  // coalesced read
    }
    __syncthreads();
    for (int r = 0; r < 4; r++) {
        int hl = ty + r * 8;
        int j  = (h0 + hl) * 4 + g;
        WhT[(size_t)j * HH + k0 + tx] = f2b(t[tx][hl]); // coalesced write
    }
}

// ---------------- proj[c][j] = sum_d emb[c,d] * W{g}x[d,hcol] + b{g}[hcol] ----------------
__global__ void k_proj(const float* __restrict__ emb,
                       const float* __restrict__ Wfx, const float* __restrict__ Wix,
                       const float* __restrict__ Wgx, const float* __restrict__ Wox,
                       const float* __restrict__ bf_, const float* __restrict__ bi_,
                       const float* __restrict__ bg_, const float* __restrict__ bo_,
                       float* __restrict__ proj) {
    int c = blockIdx.y;
    int j = blockIdx.x * 256 + threadIdx.x;   // 0..4095
    int hcol = j >> 2, g = j & 3;
    const float* Wx = (g == 0) ? Wfx : (g == 1) ? Wix : (g == 2) ? Wgx : Wox;
    const float* bb = (g == 0) ? bf_ : (g == 1) ? bi_ : (g == 2) ? bg_ : bo_;
    float acc = bb[hcol];
    const float* er = emb + (size_t)c * DD;
    for (int d = 0; d < DD; d++) {
        acc += er[d] * Wx[(size_t)d * HH + hcol];
    }
    proj[(size_t)c * G4 + j] = acc;
}

// ---------------- persistent LSTM scan: all 256 timesteps in one kernel ----------------
// 256 WGs x 128 threads (2 waves). WG(mblk = wg>>7, nblk = wg&127):
//   rows   mblk*64 .. +64   (wave wv owns rows mblk*64 + wv*32 .. +32)
//   cols   nblk*32 .. +32   (= 8 hcols x 4 gates), WhT slice held in registers (full K)
// Per step: gates = sigmoid(h @ WhT^T + proj[cls]); C,h update owned locally (C in regs).
// Cross-WG handoff of h via double-buffered global + per-step counter barrier.
__global__ __launch_bounds__(128, 1)
void k_scan(const int* __restrict__ x, const float* __restrict__ proj,
            const unsigned short* __restrict__ WhT,
            unsigned short* __restrict__ hb0, unsigned short* __restrict__ hb1,
            float* __restrict__ hf32, int* __restrict__ bar) {
    const int wg   = blockIdx.x;
    const int mblk = wg >> 7;          // 0..1
    const int nblk = wg & 127;         // 0..127
    const int tid  = threadIdx.x;
    const int lane = tid & 63;
    const int wv   = tid >> 6;         // 0..1
    const int l31  = lane & 31, half = lane >> 5;

    const int m0 = mblk * 64 + wv * 32;    // wave's first batch row
    const int n0 = nblk * 32;              // WG's first gate-col

    // ---- B fragments: WhT[n0+l31][k], k = kk*16 + half*8 + j  (256 VGPRs) ----
    short8 breg[64];
    {
        const unsigned short* Bp = WhT + (size_t)(n0 + l31) * HH + half * 8;
        #pragma unroll
        for (int kk = 0; kk < 64; kk++) breg[kk] = ld16(Bp + kk * 16);
    }

    __shared__ float sg[64][33];   // sigmoided gates [WG-local row][local col], +1 pad
    __shared__ int   cls[64];

    float Cst[4] = {0.0f, 0.0f, 0.0f, 0.0f};
    const int urow = tid >> 1;             // update: row 0..63
    const int uc0  = (tid & 1) * 4;        // update: first of 4 local hcols

    for (int s = 0; s < SS; s++) {
        const unsigned short* hin  = (s & 1) ? hb1 : hb0;
        unsigned short*       hout = (s & 1) ? hb0 : hb1;

        if (tid < 64) cls[tid] = x[(size_t)(mblk * 64 + tid) * SS + s];
        __syncthreads();

        // ---- K-loop: 64 MFMAs, A from global h, B from registers ----
        f32x16 acc0, acc1;
        #pragma unroll
        for (int r = 0; r < 16; r++) { acc0[r] = 0.0f; acc1[r] = 0.0f; }
        const unsigned short* Ap = hin + (size_t)(m0 + l31) * HH + half * 8;
        #pragma unroll
        for (int kk = 0; kk < 64; kk += 2) {
            short8 a0 = ld16(Ap + kk * 16);
            short8 a1 = ld16(Ap + kk * 16 + 16);
            acc0 = __builtin_amdgcn_mfma_f32_32x32x16_bf16(a0, breg[kk],     acc0, 0, 0, 0);
            acc1 = __builtin_amdgcn_mfma_f32_32x32x16_bf16(a1, breg[kk + 1], acc1, 0, 0, 0);
        }

        // ---- epilogue: add proj, sigmoid, stash ----
        // D layout (m74/m101): col = lane&31, row = (reg&3) + 8*(reg>>2) + 4*(lane>>5)
        {
            int jg = n0 + l31;
            #pragma unroll
            for (int r = 0; r < 16; r++) {
                int rl  = (r & 3) + 8 * (r >> 2) + 4 * half;   // 0..31
                int row = wv * 32 + rl;                        // 0..63
                float pre = acc0[r] + acc1[r] + proj[(size_t)cls[row] * G4 + jg];
                sg[row][l31] = sigm(pre);
            }
        }
        __syncthreads();

        // ---- pointwise update: thread owns (row=tid>>1, 4 hcols) ----
        {
            float rr = (cls[urow] > 0) ? 1.0f : 0.0f;
            int gb = mblk * 64 + urow;
            size_t hbase = (size_t)gb * HH + nblk * 8 + uc0;
            unsigned short hv16[4];
            #pragma unroll
            for (int q = 0; q < 4; q++) {
                float f = sg[urow][(uc0 + q) * 4 + 0];
                float i = sg[urow][(uc0 + q) * 4 + 1];
                float g = sg[urow][(uc0 + q) * 4 + 2];
                float o = sg[urow][(uc0 + q) * 4 + 3];
                float cn = (g * i + Cst[q] * f) * rr;
                Cst[q] = cn;
                float hv = o * tanh_(cn);
                hv16[q] = f2b(hv);
                if (s == SS - 1) hf32[hbase + q] = hv;
            }
            *reinterpret_cast<ushort4*>(hout + hbase) =
                make_ushort4(hv16[0], hv16[1], hv16[2], hv16[3]);
        }

        // ---- grid barrier (skip after last step) ----
        if (s < SS - 1) {
            __builtin_amdgcn_fence(__ATOMIC_RELEASE, "agent");   // flush h to coherence point
            __syncthreads();                                     // drains vmcnt for all waves
            if (tid == 0) {
                __hip_atomic_fetch_add(&bar[s], 1, __ATOMIC_RELAXED, __HIP_MEMORY_SCOPE_AGENT);
                while (__hip_atomic_load(&bar[s], __ATOMIC_RELAXED, __HIP_MEMORY_SCOPE_AGENT) < NWG) {
                    __builtin_amdgcn_s_sleep(4);
                }
            }
            __syncthreads();
            __builtin_amdgcn_fence(__ATOMIC_ACQUIRE, "agent");   // invalidate stale L1/L2
        }
    }
}

// ---------------- final projection + log_softmax ----------------
__global__ void k_final(const float* __restrict__ hf32, const float* __restrict__ Wph,
                        const float* __restrict__ bp, float* __restrict__ out) {
    __shared__ float red[128];
    int b = blockIdx.x, c = threadIdx.x;    // 128 blocks x 128 threads
    const float* hr = hf32 + (size_t)b * HH;
    float acc = bp[c];
    for (int k = 0; k < HH; k++) acc += hr[k] * Wph[(size_t)k * NCC + c];
    red[c] = acc;
    __syncthreads();
    for (int st = 64; st > 0; st >>= 1) {
        if (c < st) red[c] = fmaxf(red[c], red[c + st]);
        __syncthreads();
    }
    float m = red[0];
    __syncthreads();
    red[c] = __expf(acc - m);
    __syncthreads();
    for (int st = 64; st > 0; st >>= 1) {
        if (c < st) red[c] += red[c + st];
        __syncthreads();
    }
    out[(size_t)b * NCC + c] = acc - m - __logf(red[0]);
}

extern "C" void kernel_launch(void* const* d_in, const int* in_sizes, int n_in,
                              void* d_out, int out_size, void* d_ws, size_t ws_size,
                              hipStream_t stream) {
    const int*   x   = (const int*)  d_in[0];
    const float* emb = (const float*)d_in[1];
    const float* Wfx = (const float*)d_in[2];
    const float* Wfh = (const float*)d_in[3];
    const float* bf_ = (const float*)d_in[4];
    const float* Wix = (const float*)d_in[5];
    const float* Wih = (const float*)d_in[6];
    const float* bi_ = (const float*)d_in[7];
    const float* Wgx = (const float*)d_in[8];
    const float* Wgh = (const float*)d_in[9];
    const float* bg_ = (const float*)d_in[10];
    const float* Wox = (const float*)d_in[11];
    const float* Woh = (const float*)d_in[12];
    const float* bo_ = (const float*)d_in[13];
    const float* Wph = (const float*)d_in[14];
    const float* bp_ = (const float*)d_in[15];
    float* out = (float*)d_out;

    char* ws = (char*)d_ws;
    unsigned short* WhT  = (unsigned short*)(ws);              // 8 MB
    float*          proj = (float*)(ws + 8388608);             // 129*4096*4 ≈ 2.02 MB
    int*            bar  = (int*)(ws + 10502656);              // 1 KB
    unsigned short* hb0  = (unsigned short*)(ws + 10503680);   // 256 KB
    unsigned short* hb1  = (unsigned short*)(ws + 10765824);   // 256 KB
    float*          hf32 = (float*)(ws + 11027968);            // 512 KB
    // total ≈ 11.6 MB

    k_init<<<dim3(512), dim3(256), 0, stream>>>(hb0, bar);
    k_conv_wh<<<dim3(32, 32, 4), dim3(256), 0, stream>>>(Wfh, Wih, Wgh, Woh, WhT);
    k_proj<<<dim3(16, NCLS), dim3(256), 0, stream>>>(emb, Wfx, Wix, Wgx, Wox,
                                                     bf_, bi_, bg_, bo_, proj);
    k_scan<<<dim3(NWG), dim3(128), 0, stream>>>(x, proj, WhT, hb0, hb1, hf32, bar);
    k_final<<<dim3(128), dim3(128), 0, stream>>>(hf32, Wph, bp_, out);
}

// Round 3
// 2566.868 us; speedup vs baseline: 3.4295x; 3.4295x over previous
//
#include <hip/hip_runtime.h>
#include <hip/hip_bf16.h>

#define BB   128
#define SS   256
#define DD   512
#define HH   1024
#define NCC  128
#define NCLS 129
#define G4   4096   // 4*HH, gate-interleaved: j = hcol*4 + gate (f,i,g,o)
#define NWG  256    // persistent grid size

typedef __attribute__((ext_vector_type(8)))  short  short8;
typedef __attribute__((ext_vector_type(16))) float  f32x16;

static __device__ __forceinline__ float sigm(float x)  { return 1.0f / (1.0f + __expf(-x)); }
static __device__ __forceinline__ float tanh_(float x) { return 1.0f - 2.0f / (__expf(2.0f * x) + 1.0f); }
static __device__ __forceinline__ unsigned short f2b(float v) {
    __hip_bfloat16 h = __float2bfloat16(v);
    return *reinterpret_cast<unsigned short*>(&h);
}
static __device__ __forceinline__ short8 ld16(const unsigned short* p) {
    return *reinterpret_cast<const short8*>(p);
}

// ---------------- zero-init h buffer 0 and barrier block ----------------
__global__ void k_init(unsigned short* __restrict__ hb0, int* __restrict__ bar) {
    int i = blockIdx.x * 256 + threadIdx.x;
    if (i < BB * HH) hb0[i] = 0;
    if (i < 1024) bar[i] = 0;    // leaves (8 x 64 ints), root @512, go @576
}

// ---------------- Wh -> bf16, transposed, gate-interleaved ----------------
__global__ void k_conv_wh(const float* __restrict__ Wfh, const float* __restrict__ Wih,
                          const float* __restrict__ Wgh, const float* __restrict__ Woh,
                          unsigned short* __restrict__ WhT) {
    __shared__ float t[32][33];
    int g = blockIdx.z;
    const float* W = (g == 0) ? Wfh : (g == 1) ? Wih : (g == 2) ? Wgh : Woh;
    int h0 = blockIdx.x * 32, k0 = blockIdx.y * 32;
    int tx = threadIdx.x & 31, ty = threadIdx.x >> 5;
    for (int r = 0; r < 4; r++) {
        int k = ty + r * 8;
        t[k][tx] = W[(size_t)(k0 + k) * HH + h0 + tx];
    }
    __syncthreads();
    for (int r = 0; r < 4; r++) {
        int hl = ty + r * 8;
        int j  = (h0 + hl) * 4 + g;
        WhT[(size_t)j * HH + k0 + tx] = f2b(t[tx][hl]);
    }
}

// ---------------- proj[c][j] = emb[c,:] @ Wx[:,hcol] + b ----------------
__global__ void k_proj(const float* __restrict__ emb,
                       const float* __restrict__ Wfx, const float* __restrict__ Wix,
                       const float* __restrict__ Wgx, const float* __restrict__ Wox,
                       const float* __restrict__ bf_, const float* __restrict__ bi_,
                       const float* __restrict__ bg_, const float* __restrict__ bo_,
                       float* __restrict__ proj) {
    int c = blockIdx.y;
    int j = blockIdx.x * 256 + threadIdx.x;
    int hcol = j >> 2, g = j & 3;
    const float* Wx = (g == 0) ? Wfx : (g == 1) ? Wix : (g == 2) ? Wgx : Wox;
    const float* bb = (g == 0) ? bf_ : (g == 1) ? bi_ : (g == 2) ? bg_ : bo_;
    float acc = bb[hcol];
    const float* er = emb + (size_t)c * DD;
    for (int d = 0; d < DD; d++) acc += er[d] * Wx[(size_t)d * HH + hcol];
    proj[(size_t)c * G4 + j] = acc;
}

// ---- L2-bypassing 16B load (reads L3 coherence point; h is cross-XCD dynamic data)
#define LDA(d, L) asm volatile("global_load_dwordx4 %0, %1, off offset:" L " sc0 sc1" \
                               : "=v"(d) : "v"(ab))
// ---- waitcnt with data-tie so MFMAs can't be scheduled before the wait
#define WAITA(N, A) asm volatile("s_waitcnt vmcnt(" N ")" : \
    "+v"(A[0]),"+v"(A[1]),"+v"(A[2]),"+v"(A[3]),"+v"(A[4]),"+v"(A[5]),"+v"(A[6]),"+v"(A[7]), \
    "+v"(A[8]),"+v"(A[9]),"+v"(A[10]),"+v"(A[11]),"+v"(A[12]),"+v"(A[13]),"+v"(A[14]),"+v"(A[15]))

#define MF16(A, KB) do { \
    acc0 = __builtin_amdgcn_mfma_f32_32x32x16_bf16(A[0],  breg[(KB)+0],  acc0, 0,0,0); \
    acc1 = __builtin_amdgcn_mfma_f32_32x32x16_bf16(A[1],  breg[(KB)+1],  acc1, 0,0,0); \
    acc0 = __builtin_amdgcn_mfma_f32_32x32x16_bf16(A[2],  breg[(KB)+2],  acc0, 0,0,0); \
    acc1 = __builtin_amdgcn_mfma_f32_32x32x16_bf16(A[3],  breg[(KB)+3],  acc1, 0,0,0); \
    acc0 = __builtin_amdgcn_mfma_f32_32x32x16_bf16(A[4],  breg[(KB)+4],  acc0, 0,0,0); \
    acc1 = __builtin_amdgcn_mfma_f32_32x32x16_bf16(A[5],  breg[(KB)+5],  acc1, 0,0,0); \
    acc0 = __builtin_amdgcn_mfma_f32_32x32x16_bf16(A[6],  breg[(KB)+6],  acc0, 0,0,0); \
    acc1 = __builtin_amdgcn_mfma_f32_32x32x16_bf16(A[7],  breg[(KB)+7],  acc1, 0,0,0); \
    acc0 = __builtin_amdgcn_mfma_f32_32x32x16_bf16(A[8],  breg[(KB)+8],  acc0, 0,0,0); \
    acc1 = __builtin_amdgcn_mfma_f32_32x32x16_bf16(A[9],  breg[(KB)+9],  acc1, 0,0,0); \
    acc0 = __builtin_amdgcn_mfma_f32_32x32x16_bf16(A[10], breg[(KB)+10], acc0, 0,0,0); \
    acc1 = __builtin_amdgcn_mfma_f32_32x32x16_bf16(A[11], breg[(KB)+11], acc1, 0,0,0); \
    acc0 = __builtin_amdgcn_mfma_f32_32x32x16_bf16(A[12], breg[(KB)+12], acc0, 0,0,0); \
    acc1 = __builtin_amdgcn_mfma_f32_32x32x16_bf16(A[13], breg[(KB)+13], acc1, 0,0,0); \
    acc0 = __builtin_amdgcn_mfma_f32_32x32x16_bf16(A[14], breg[(KB)+14], acc0, 0,0,0); \
    acc1 = __builtin_amdgcn_mfma_f32_32x32x16_bf16(A[15], breg[(KB)+15], acc1, 0,0,0); \
} while (0)

// ---------------- persistent LSTM scan ----------------
// 256 WGs x 128 thr (2 waves). WG(mg = wg&3, ng = wg>>2): rows mg*32..+32,
// gate-cols ng*64..+64 (wave wv: +wv*32..+32). WhT slice in registers (full K).
// h handoff: sc0sc1 write-through stores -> L3; sc0sc1 loads <- L3. No fences.
// Grid barrier: cumulative tree (8 leaves + root + go), relaxed agent atomics.
__global__ __launch_bounds__(128, 1)
void k_scan(const int* __restrict__ x, const float* __restrict__ proj,
            const unsigned short* __restrict__ WhT,
            unsigned short* __restrict__ hb0, unsigned short* __restrict__ hb1,
            float* __restrict__ hf32, int* __restrict__ bar) {
    const int wg = blockIdx.x, tid = threadIdx.x;
    const int lane = tid & 63, wv = tid >> 6;
    const int l31 = lane & 31, half = lane >> 5;
    const int mg = wg & 3, ng = wg >> 2;
    const int m0 = mg * 32, n0 = ng * 64;

    // B fragments: WhT[n0+wv*32+l31][k], k = kk*16 + half*8 + j  (256 VGPRs/AGPRs)
    short8 breg[64];
    {
        const unsigned short* Bp = WhT + (size_t)(n0 + wv * 32 + l31) * HH + half * 8;
        #pragma unroll
        for (int kk = 0; kk < 64; kk++) breg[kk] = ld16(Bp + kk * 16);
    }

    __shared__ float sg[32][68];    // sigmoided gates [row][gate-col], 16B-aligned rows
    __shared__ int   clsS[2][32];   // double-buffered class ids (prefetched)

    float Cst[4] = {0.0f, 0.0f, 0.0f, 0.0f};
    const int urow = tid & 31, uq = tid >> 5;   // pointwise: row, hcol-quad

    if (tid < 32) clsS[0][tid] = x[(size_t)(m0 + tid) * SS];
    __syncthreads();

    const unsigned long long ab0 =
        (unsigned long long)(hb0 + (size_t)(m0 + l31) * HH + half * 8);
    const unsigned long long ab1 =
        (unsigned long long)(hb1 + (size_t)(m0 + l31) * HH + half * 8);

    for (int s = 0; s < SS; s++) {
        const int cur = s & 1;
        const unsigned long long ab = cur ? ab1 : ab0;
        unsigned short* hout = cur ? hb0 : hb1;

        // ---- pipelined A loads: 4 chunks x 16 x 16B, offsets kk*32 bytes ----
        short8 a0[16], a1[16], a2[16], a3[16];
        LDA(a0[0],"0");    LDA(a0[1],"32");   LDA(a0[2],"64");   LDA(a0[3],"96");
        LDA(a0[4],"128");  LDA(a0[5],"160");  LDA(a0[6],"192");  LDA(a0[7],"224");
        LDA(a0[8],"256");  LDA(a0[9],"288");  LDA(a0[10],"320"); LDA(a0[11],"352");
        LDA(a0[12],"384"); LDA(a0[13],"416"); LDA(a0[14],"448"); LDA(a0[15],"480");
        LDA(a1[0],"512");  LDA(a1[1],"544");  LDA(a1[2],"576");  LDA(a1[3],"608");
        LDA(a1[4],"640");  LDA(a1[5],"672");  LDA(a1[6],"704");  LDA(a1[7],"736");
        LDA(a1[8],"768");  LDA(a1[9],"800");  LDA(a1[10],"832"); LDA(a1[11],"864");
        LDA(a1[12],"896"); LDA(a1[13],"928"); LDA(a1[14],"960"); LDA(a1[15],"992");

        f32x16 acc0, acc1;
        #pragma unroll
        for (int r = 0; r < 16; r++) { acc0[r] = 0.0f; acc1[r] = 0.0f; }

        WAITA("16", a0);            // c0 complete (c1 in flight)
        LDA(a2[0],"1024"); LDA(a2[1],"1056"); LDA(a2[2],"1088"); LDA(a2[3],"1120");
        LDA(a2[4],"1152"); LDA(a2[5],"1184"); LDA(a2[6],"1216"); LDA(a2[7],"1248");
        LDA(a2[8],"1280"); LDA(a2[9],"1312"); LDA(a2[10],"1344");LDA(a2[11],"1376");
        LDA(a2[12],"1408");LDA(a2[13],"1440");LDA(a2[14],"1472");LDA(a2[15],"1504");
        MF16(a0, 0);
        WAITA("16", a1);            // c1 complete (c2 in flight)
        LDA(a3[0],"1536"); LDA(a3[1],"1568"); LDA(a3[2],"1600"); LDA(a3[3],"1632");
        LDA(a3[4],"1664"); LDA(a3[5],"1696"); LDA(a3[6],"1728"); LDA(a3[7],"1760");
        LDA(a3[8],"1792"); LDA(a3[9],"1824"); LDA(a3[10],"1856");LDA(a3[11],"1888");
        LDA(a3[12],"1920");LDA(a3[13],"1952");LDA(a3[14],"1984");LDA(a3[15],"2016");
        MF16(a1, 16);
        WAITA("16", a2);            // c2 complete (c3 in flight)
        MF16(a2, 32);
        WAITA("0", a3);             // all done
        MF16(a3, 48);

        // ---- epilogue: add proj, sigmoid, stash in LDS ----
        // C/D layout (m74/m101): col = lane&31, row = (r&3) + 8*(r>>2) + 4*(lane>>5)
        {
            const int jg = n0 + wv * 32 + l31;
            #pragma unroll
            for (int r = 0; r < 16; r++) {
                int row = (r & 3) + 8 * (r >> 2) + 4 * half;
                float pre = acc0[r] + acc1[r] + proj[(size_t)clsS[cur][row] * G4 + jg];
                sg[row][wv * 32 + l31] = sigm(pre);
            }
        }
        __syncthreads();

        // ---- pointwise: thread owns (row = tid&31, 4 hcols = (tid>>5)*4..) ----
        {
            const int cb = clsS[cur][urow];
            const float rr = (cb > 0) ? 1.0f : 0.0f;
            const size_t hoff = (size_t)(m0 + urow) * HH + ng * 16 + uq * 4;
            unsigned short hv[4];
            #pragma unroll
            for (int q = 0; q < 4; q++) {
                float4 gq = *reinterpret_cast<const float4*>(&sg[urow][uq * 16 + q * 4]);
                float cn = (gq.z * gq.y + Cst[q] * gq.x) * rr;   // (g*i + C*f)*r
                Cst[q] = cn;
                float hvv = gq.w * tanh_(cn);
                hv[q] = f2b(hvv);
                if (s == SS - 1) hf32[hoff + q] = hvv;
            }
            unsigned long long pk = (unsigned long long)hv[0]
                                  | ((unsigned long long)hv[1] << 16)
                                  | ((unsigned long long)hv[2] << 32)
                                  | ((unsigned long long)hv[3] << 48);
            unsigned long long ha = (unsigned long long)(hout + hoff);
            // write-through past L2 to the L3 coherence point
            asm volatile("global_store_dwordx2 %0, %1, off sc0 sc1" :: "v"(ha), "v"(pk) : "memory");
            // prefetch next step's class ids (drained by pre-barrier syncthreads)
            if (s + 1 < SS && tid < 32)
                clsS[cur ^ 1][tid] = x[(size_t)(m0 + tid) * SS + s + 1];
        }

        // ---- fence-free tree grid barrier ----
        if (s < SS - 1) {
            __syncthreads();   // drains vmcnt: h write-through stores acked at L3
            if (tid == 0) {
                const int leaf = wg >> 5;
                int t = __hip_atomic_fetch_add(&bar[leaf * 64], 1,
                                               __ATOMIC_RELAXED, __HIP_MEMORY_SCOPE_AGENT);
                if (t == 32 * (s + 1) - 1) {
                    int r2 = __hip_atomic_fetch_add(&bar[512], 1,
                                                    __ATOMIC_RELAXED, __HIP_MEMORY_SCOPE_AGENT);
                    if (r2 == 8 * (s + 1) - 1)
                        __hip_atomic_store(&bar[576], s + 1,
                                           __ATOMIC_RELAXED, __HIP_MEMORY_SCOPE_AGENT);
                }
                while (__hip_atomic_load(&bar[576], __ATOMIC_RELAXED,
                                         __HIP_MEMORY_SCOPE_AGENT) < s + 1)
                    __builtin_amdgcn_s_sleep(2);
            }
            __syncthreads();
        }
    }
}

// ---------------- final projection + log_softmax ----------------
__global__ void k_final(const float* __restrict__ hf32, const float* __restrict__ Wph,
                        const float* __restrict__ bp, float* __restrict__ out) {
    __shared__ float red[128];
    int b = blockIdx.x, c = threadIdx.x;
    const float* hr = hf32 + (size_t)b * HH;
    float acc = bp[c];
    for (int k = 0; k < HH; k++) acc += hr[k] * Wph[(size_t)k * NCC + c];
    red[c] = acc;
    __syncthreads();
    for (int st = 64; st > 0; st >>= 1) {
        if (c < st) red[c] = fmaxf(red[c], red[c + st]);
        __syncthreads();
    }
    float m = red[0];
    __syncthreads();
    red[c] = __expf(acc - m);
    __syncthreads();
    for (int st = 64; st > 0; st >>= 1) {
        if (c < st) red[c] += red[c + st];
        __syncthreads();
    }
    out[(size_t)b * NCC + c] = acc - m - __logf(red[0]);
}

extern "C" void kernel_launch(void* const* d_in, const int* in_sizes, int n_in,
                              void* d_out, int out_size, void* d_ws, size_t ws_size,
                              hipStream_t stream) {
    const int*   x   = (const int*)  d_in[0];
    const float* emb = (const float*)d_in[1];
    const float* Wfx = (const float*)d_in[2];
    const float* Wfh = (const float*)d_in[3];
    const float* bf_ = (const float*)d_in[4];
    const float* Wix = (const float*)d_in[5];
    const float* Wih = (const float*)d_in[6];
    const float* bi_ = (const float*)d_in[7];
    const float* Wgx = (const float*)d_in[8];
    const float* Wgh = (const float*)d_in[9];
    const float* bg_ = (const float*)d_in[10];
    const float* Wox = (const float*)d_in[11];
    const float* Woh = (const float*)d_in[12];
    const float* bo_ = (const float*)d_in[13];
    const float* Wph = (const float*)d_in[14];
    const float* bp_ = (const float*)d_in[15];
    float* out = (float*)d_out;

    char* ws = (char*)d_ws;
    unsigned short* WhT  = (unsigned short*)(ws);              // 8 MB
    float*          proj = (float*)(ws + 8388608);             // 2.02 MB -> ends 10502144
    int*            bar  = (int*)(ws + 10502656);              // 4 KB (1024 ints)
    unsigned short* hb0  = (unsigned short*)(ws + 10506752);   // 256 KB
    unsigned short* hb1  = (unsigned short*)(ws + 10768896);   // 256 KB
    float*          hf32 = (float*)(ws + 11031040);            // 512 KB -> ends ~11.56 MB

    k_init<<<dim3(512), dim3(256), 0, stream>>>(hb0, bar);
    k_conv_wh<<<dim3(32, 32, 4), dim3(256), 0, stream>>>(Wfh, Wih, Wgh, Woh, WhT);
    k_proj<<<dim3(16, NCLS), dim3(256), 0, stream>>>(emb, Wfx, Wix, Wgx, Wox,
                                                     bf_, bi_, bg_, bo_, proj);
    k_scan<<<dim3(NWG), dim3(128), 0, stream>>>(x, proj, WhT, hb0, hb1, hf32, bar);
    k_final<<<dim3(128), dim3(128), 0, stream>>>(hf32, Wph, bp_, out);
}

// Round 4
// 2336.957 us; speedup vs baseline: 3.7669x; 1.0984x over previous
//
#include <hip/hip_runtime.h>
#include <hip/hip_bf16.h>

#define BB   128
#define SS   256
#define DD   512
#define HH   1024
#define NCC  128
#define NCLS 129
#define G4   4096   // 4*HH, gate-interleaved: j = hcol*4 + gate (f,i,g,o)
#define NWG  256    // persistent grid size

typedef __attribute__((ext_vector_type(8)))  short  short8;
typedef __attribute__((ext_vector_type(16))) float  f32x16;

static __device__ __forceinline__ float sigm(float x)  { return 1.0f / (1.0f + __expf(-x)); }
static __device__ __forceinline__ float tanh_(float x) { return 1.0f - 2.0f / (__expf(2.0f * x) + 1.0f); }
static __device__ __forceinline__ unsigned short f2b(float v) {
    __hip_bfloat16 h = __float2bfloat16(v);
    return *reinterpret_cast<unsigned short*>(&h);
}
static __device__ __forceinline__ short8 ld16(const unsigned short* p) {
    return *reinterpret_cast<const short8*>(p);
}

// ---------------- zero-init h buffer 0 and flag block ----------------
__global__ void k_init(unsigned short* __restrict__ hb0, int* __restrict__ flags) {
    int i = blockIdx.x * 256 + threadIdx.x;
    if (i < BB * HH) hb0[i] = 0;
    if (i < 8192) flags[i] = 0;   // 256 slots x 32 ints (128B stride)
}

// ---------------- Wh -> bf16, transposed, gate-interleaved ----------------
__global__ void k_conv_wh(const float* __restrict__ Wfh, const float* __restrict__ Wih,
                          const float* __restrict__ Wgh, const float* __restrict__ Woh,
                          unsigned short* __restrict__ WhT) {
    __shared__ float t[32][33];
    int g = blockIdx.z;
    const float* W = (g == 0) ? Wfh : (g == 1) ? Wih : (g == 2) ? Wgh : Woh;
    int h0 = blockIdx.x * 32, k0 = blockIdx.y * 32;
    int tx = threadIdx.x & 31, ty = threadIdx.x >> 5;
    for (int r = 0; r < 4; r++) {
        int k = ty + r * 8;
        t[k][tx] = W[(size_t)(k0 + k) * HH + h0 + tx];
    }
    __syncthreads();
    for (int r = 0; r < 4; r++) {
        int hl = ty + r * 8;
        int j  = (h0 + hl) * 4 + g;
        WhT[(size_t)j * HH + k0 + tx] = f2b(t[tx][hl]);
    }
}

// ---------------- proj[c][j] = emb[c,:] @ Wx[:,hcol] + b ----------------
__global__ void k_proj(const float* __restrict__ emb,
                       const float* __restrict__ Wfx, const float* __restrict__ Wix,
                       const float* __restrict__ Wgx, const float* __restrict__ Wox,
                       const float* __restrict__ bf_, const float* __restrict__ bi_,
                       const float* __restrict__ bg_, const float* __restrict__ bo_,
                       float* __restrict__ proj) {
    int c = blockIdx.y;
    int j = blockIdx.x * 256 + threadIdx.x;
    int hcol = j >> 2, g = j & 3;
    const float* Wx = (g == 0) ? Wfx : (g == 1) ? Wix : (g == 2) ? Wgx : Wox;
    const float* bb = (g == 0) ? bf_ : (g == 1) ? bi_ : (g == 2) ? bg_ : bo_;
    float acc = bb[hcol];
    const float* er = emb + (size_t)c * DD;
    for (int d = 0; d < DD; d++) acc += er[d] * Wx[(size_t)d * HH + hcol];
    proj[(size_t)c * G4 + j] = acc;
}

// ---- L2-bypassing 16B load (reads L3 coherence point; h is cross-XCD dynamic data)
#define LDA(d, L) asm volatile("global_load_dwordx4 %0, %1, off offset:" L " sc0 sc1" \
                               : "=v"(d) : "v"(ab))
// ---- waitcnt with data-tie so MFMAs can't be scheduled before the wait
#define WAITA(N, A) asm volatile("s_waitcnt vmcnt(" N ")" : \
    "+v"(A[0]),"+v"(A[1]),"+v"(A[2]),"+v"(A[3]),"+v"(A[4]),"+v"(A[5]),"+v"(A[6]),"+v"(A[7]), \
    "+v"(A[8]),"+v"(A[9]),"+v"(A[10]),"+v"(A[11]),"+v"(A[12]),"+v"(A[13]),"+v"(A[14]),"+v"(A[15]))

#define MF16(A, KB) do { \
    acc0 = __builtin_amdgcn_mfma_f32_32x32x16_bf16(A[0],  breg[(KB)+0],  acc0, 0,0,0); \
    acc1 = __builtin_amdgcn_mfma_f32_32x32x16_bf16(A[1],  breg[(KB)+1],  acc1, 0,0,0); \
    acc0 = __builtin_amdgcn_mfma_f32_32x32x16_bf16(A[2],  breg[(KB)+2],  acc0, 0,0,0); \
    acc1 = __builtin_amdgcn_mfma_f32_32x32x16_bf16(A[3],  breg[(KB)+3],  acc1, 0,0,0); \
    acc0 = __builtin_amdgcn_mfma_f32_32x32x16_bf16(A[4],  breg[(KB)+4],  acc0, 0,0,0); \
    acc1 = __builtin_amdgcn_mfma_f32_32x32x16_bf16(A[5],  breg[(KB)+5],  acc1, 0,0,0); \
    acc0 = __builtin_amdgcn_mfma_f32_32x32x16_bf16(A[6],  breg[(KB)+6],  acc0, 0,0,0); \
    acc1 = __builtin_amdgcn_mfma_f32_32x32x16_bf16(A[7],  breg[(KB)+7],  acc1, 0,0,0); \
    acc0 = __builtin_amdgcn_mfma_f32_32x32x16_bf16(A[8],  breg[(KB)+8],  acc0, 0,0,0); \
    acc1 = __builtin_amdgcn_mfma_f32_32x32x16_bf16(A[9],  breg[(KB)+9],  acc1, 0,0,0); \
    acc0 = __builtin_amdgcn_mfma_f32_32x32x16_bf16(A[10], breg[(KB)+10], acc0, 0,0,0); \
    acc1 = __builtin_amdgcn_mfma_f32_32x32x16_bf16(A[11], breg[(KB)+11], acc1, 0,0,0); \
    acc0 = __builtin_amdgcn_mfma_f32_32x32x16_bf16(A[12], breg[(KB)+12], acc0, 0,0,0); \
    acc1 = __builtin_amdgcn_mfma_f32_32x32x16_bf16(A[13], breg[(KB)+13], acc1, 0,0,0); \
    acc0 = __builtin_amdgcn_mfma_f32_32x32x16_bf16(A[14], breg[(KB)+14], acc0, 0,0,0); \
    acc1 = __builtin_amdgcn_mfma_f32_32x32x16_bf16(A[15], breg[(KB)+15], acc1, 0,0,0); \
} while (0)

// 16 gathered proj loads (normal caching), completed by the poll's vmcnt(0)
#define PRLOAD(DSTA, CLSBUF) do { \
    _Pragma("unroll") \
    for (int r = 0; r < 16; r++) { \
        int row = (r & 3) + 8 * (r >> 2) + 4 * half; \
        const float* pa = proj + (size_t)CLSBUF[row] * G4 + jg; \
        asm volatile("global_load_dword %0, %1, off" : "=v"(DSTA[r]) \
                     : "v"((unsigned long long)pa)); \
    } \
} while (0)

// ---------------- persistent LSTM scan ----------------
// 256 WGs x 128 thr (2 waves). WG(mg = wg&3, ng = wg>>2): rows mg*32..+32,
// gate-cols ng*64..+64 (wave wv: +wv*32..+32). WhT slice in registers (full K).
// h handoff: sc0sc1 write-through stores -> L3; sc0sc1 loads <- L3.
// Sync: 4 independent row-groups (mg). Flag array (128B-strided), no atomics:
// post flags[wg]=s+1, every wave polls its group's 64 flags with one lane-
// parallel load + ballot. No post-poll __syncthreads (LDS hazards covered by
// the pre-flag barrier; waves stay within one step of each other).
__global__ __launch_bounds__(128, 1)
void k_scan(const int* __restrict__ x, const float* __restrict__ proj,
            const unsigned short* __restrict__ WhT,
            unsigned short* __restrict__ hb0, unsigned short* __restrict__ hb1,
            float* __restrict__ hf32, int* __restrict__ flags) {
    const int wg = blockIdx.x, tid = threadIdx.x;
    const int lane = tid & 63, wv = tid >> 6;
    const int l31 = lane & 31, half = lane >> 5;
    const int mg = wg & 3, ng = wg >> 2;
    const int m0 = mg * 32, n0 = ng * 64;
    const int jg = n0 + wv * 32 + l31;       // this lane's gate-col

    // B fragments: WhT[jg][k], k = kk*16 + half*8 + j  (256 regs)
    short8 breg[64];
    {
        const unsigned short* Bp = WhT + (size_t)jg * HH + half * 8;
        #pragma unroll
        for (int kk = 0; kk < 64; kk++) breg[kk] = ld16(Bp + kk * 16);
    }

    __shared__ float sg[32][68];    // sigmoided gates [row][gate-col]
    __shared__ int   clsS[2][32];   // double-buffered class ids

    float Cst[4] = {0.0f, 0.0f, 0.0f, 0.0f};
    const int urow = tid & 31, uq = tid >> 5;

    if (tid < 32) clsS[0][tid] = x[(size_t)(m0 + tid) * SS];
    __syncthreads();

    const unsigned long long ab0 =
        (unsigned long long)(hb0 + (size_t)(m0 + l31) * HH + half * 8);
    const unsigned long long ab1 =
        (unsigned long long)(hb1 + (size_t)(m0 + l31) * HH + half * 8);
    const unsigned long long postAddr = (unsigned long long)(flags + (size_t)wg * 32);
    const unsigned long long pollAddr =
        (unsigned long long)(flags + ((size_t)(lane << 2) + mg) * 32);

    float pr[16];
    PRLOAD(pr, clsS[0]);            // step-0 proj gather (drained by first WAITA)

    for (int s = 0; s < SS; s++) {
        const int cur = s & 1;
        const unsigned long long ab = cur ? ab1 : ab0;
        unsigned short* hout = cur ? hb0 : hb1;

        // ---- pipelined A loads: 4 chunks x 16 x 16B ----
        short8 a0[16], a1[16], a2[16], a3[16];
        LDA(a0[0],"0");    LDA(a0[1],"32");   LDA(a0[2],"64");   LDA(a0[3],"96");
        LDA(a0[4],"128");  LDA(a0[5],"160");  LDA(a0[6],"192");  LDA(a0[7],"224");
        LDA(a0[8],"256");  LDA(a0[9],"288");  LDA(a0[10],"320"); LDA(a0[11],"352");
        LDA(a0[12],"384"); LDA(a0[13],"416"); LDA(a0[14],"448"); LDA(a0[15],"480");
        LDA(a1[0],"512");  LDA(a1[1],"544");  LDA(a1[2],"576");  LDA(a1[3],"608");
        LDA(a1[4],"640");  LDA(a1[5],"672");  LDA(a1[6],"704");  LDA(a1[7],"736");
        LDA(a1[8],"768");  LDA(a1[9],"800");  LDA(a1[10],"832"); LDA(a1[11],"864");
        LDA(a1[12],"896"); LDA(a1[13],"928"); LDA(a1[14],"960"); LDA(a1[15],"992");

        f32x16 acc0, acc1;
        #pragma unroll
        for (int r = 0; r < 16; r++) { acc0[r] = 0.0f; acc1[r] = 0.0f; }

        WAITA("16", a0);
        LDA(a2[0],"1024"); LDA(a2[1],"1056"); LDA(a2[2],"1088"); LDA(a2[3],"1120");
        LDA(a2[4],"1152"); LDA(a2[5],"1184"); LDA(a2[6],"1216"); LDA(a2[7],"1248");
        LDA(a2[8],"1280"); LDA(a2[9],"1312"); LDA(a2[10],"1344");LDA(a2[11],"1376");
        LDA(a2[12],"1408");LDA(a2[13],"1440");LDA(a2[14],"1472");LDA(a2[15],"1504");
        MF16(a0, 0);
        WAITA("16", a1);
        LDA(a3[0],"1536"); LDA(a3[1],"1568"); LDA(a3[2],"1600"); LDA(a3[3],"1632");
        LDA(a3[4],"1664"); LDA(a3[5],"1696"); LDA(a3[6],"1728"); LDA(a3[7],"1760");
        LDA(a3[8],"1792"); LDA(a3[9],"1824"); LDA(a3[10],"1856");LDA(a3[11],"1888");
        LDA(a3[12],"1920");LDA(a3[13],"1952");LDA(a3[14],"1984");LDA(a3[15],"2016");
        MF16(a1, 16);
        WAITA("16", a2);
        MF16(a2, 32);
        WAITA("0", a3);
        MF16(a3, 48);

        // ---- epilogue: add preloaded proj, sigmoid, stash in LDS ----
        // C/D layout (m74/m101): col = lane&31, row = (r&3) + 8*(r>>2) + 4*(lane>>5)
        #pragma unroll
        for (int r = 0; r < 16; r++) {
            int row = (r & 3) + 8 * (r >> 2) + 4 * half;
            sg[row][wv * 32 + l31] = sigm(acc0[r] + acc1[r] + pr[r]);
        }
        __syncthreads();

        // ---- pointwise: thread owns (row = tid&31, hcols uq*4..+4) ----
        {
            const float rr = (clsS[cur][urow] > 0) ? 1.0f : 0.0f;
            const size_t hoff = (size_t)(m0 + urow) * HH + ng * 16 + uq * 4;
            unsigned short hv[4];
            #pragma unroll
            for (int q = 0; q < 4; q++) {
                float4 gq = *reinterpret_cast<const float4*>(&sg[urow][uq * 16 + q * 4]);
                float cn = (gq.z * gq.y + Cst[q] * gq.x) * rr;   // (g*i + C*f)*r
                Cst[q] = cn;
                float hvv = gq.w * tanh_(cn);
                hv[q] = f2b(hvv);
                if (s == SS - 1) hf32[hoff + q] = hvv;
            }
            unsigned long long pk = (unsigned long long)hv[0]
                                  | ((unsigned long long)hv[1] << 16)
                                  | ((unsigned long long)hv[2] << 32)
                                  | ((unsigned long long)hv[3] << 48);
            unsigned long long ha = (unsigned long long)(hout + hoff);
            asm volatile("global_store_dwordx2 %0, %1, off sc0 sc1" :: "v"(ha), "v"(pk) : "memory");
            if (s + 1 < SS && tid < 32)
                clsS[cur ^ 1][tid] = x[(size_t)(m0 + tid) * SS + s + 1];
        }

        // ---- flag barrier (4 independent mg-groups) ----
        if (s < SS - 1) {
            asm volatile("s_waitcnt vmcnt(0)" ::: "memory");   // per-wave h-store drain
            __syncthreads();                                   // both waves drained + clsS ready
            if (tid == 0) {
                int fv = s + 1;
                asm volatile("global_store_dword %0, %1, off sc0 sc1"
                             :: "v"(postAddr), "v"(fv) : "memory");
            }
            PRLOAD(pr, clsS[cur ^ 1]);     // next step's proj gather, rides the poll
            int got;
            do {
                asm volatile("global_load_dword %0, %1, off sc0 sc1\n\t"
                             "s_waitcnt vmcnt(0)"
                             : "=v"(got) : "v"(pollAddr) : "memory");
            } while (__ballot(got >= s + 1) != ~0ull);
        }
    }
}

// ---------------- final projection + log_softmax ----------------
__global__ void k_final(const float* __restrict__ hf32, const float* __restrict__ Wph,
                        const float* __restrict__ bp, float* __restrict__ out) {
    __shared__ float red[128];
    int b = blockIdx.x, c = threadIdx.x;
    const float* hr = hf32 + (size_t)b * HH;
    float acc = bp[c];
    for (int k = 0; k < HH; k++) acc += hr[k] * Wph[(size_t)k * NCC + c];
    red[c] = acc;
    __syncthreads();
    for (int st = 64; st > 0; st >>= 1) {
        if (c < st) red[c] = fmaxf(red[c], red[c + st]);
        __syncthreads();
    }
    float m = red[0];
    __syncthreads();
    red[c] = __expf(acc - m);
    __syncthreads();
    for (int st = 64; st > 0; st >>= 1) {
        if (c < st) red[c] += red[c + st];
        __syncthreads();
    }
    out[(size_t)b * NCC + c] = acc - m - __logf(red[0]);
}

extern "C" void kernel_launch(void* const* d_in, const int* in_sizes, int n_in,
                              void* d_out, int out_size, void* d_ws, size_t ws_size,
                              hipStream_t stream) {
    const int*   x   = (const int*)  d_in[0];
    const float* emb = (const float*)d_in[1];
    const float* Wfx = (const float*)d_in[2];
    const float* Wfh = (const float*)d_in[3];
    const float* bf_ = (const float*)d_in[4];
    const float* Wix = (const float*)d_in[5];
    const float* Wih = (const float*)d_in[6];
    const float* bi_ = (const float*)d_in[7];
    const float* Wgx = (const float*)d_in[8];
    const float* Wgh = (const float*)d_in[9];
    const float* bg_ = (const float*)d_in[10];
    const float* Wox = (const float*)d_in[11];
    const float* Woh = (const float*)d_in[12];
    const float* bo_ = (const float*)d_in[13];
    const float* Wph = (const float*)d_in[14];
    const float* bp_ = (const float*)d_in[15];
    float* out = (float*)d_out;

    char* ws = (char*)d_ws;
    unsigned short* WhT   = (unsigned short*)(ws);              // 8 MB
    float*          proj  = (float*)(ws + 8388608);             // 2.02 MB -> ends 10502144
    int*            flags = (int*)(ws + 10502656);              // 32 KB (256 x 128B)
    unsigned short* hb0   = (unsigned short*)(ws + 10535424);   // 256 KB
    unsigned short* hb1   = (unsigned short*)(ws + 10797568);   // 256 KB
    float*          hf32  = (float*)(ws + 11059712);            // 512 KB -> ends ~11.58 MB

    k_init<<<dim3(512), dim3(256), 0, stream>>>(hb0, flags);
    k_conv_wh<<<dim3(32, 32, 4), dim3(256), 0, stream>>>(Wfh, Wih, Wgh, Woh, WhT);
    k_proj<<<dim3(16, NCLS), dim3(256), 0, stream>>>(emb, Wfx, Wix, Wgx, Wox,
                                                     bf_, bi_, bg_, bo_, proj);
    k_scan<<<dim3(NWG), dim3(128), 0, stream>>>(x, proj, WhT, hb0, hb1, hf32, flags);
    k_final<<<dim3(128), dim3(128), 0, stream>>>(hf32, Wph, bp_, out);
}

// Round 5
// 1471.918 us; speedup vs baseline: 5.9807x; 1.5877x over previous
//
#include <hip/hip_runtime.h>
#include <hip/hip_bf16.h>

#define BB   128
#define SS   256
#define DD   512
#define HH   1024
#define NCC  128
#define NCLS 129
#define G4   4096   // 4*HH, gate-interleaved: j = hcol*4 + gate (f,i,g,o)
#define NWG  256    // persistent grid size

typedef __attribute__((ext_vector_type(8)))  short  short8;
typedef __attribute__((ext_vector_type(16))) float  f32x16;

static __device__ __forceinline__ float sigm(float x)  { return 1.0f / (1.0f + __expf(-x)); }
static __device__ __forceinline__ float tanh_(float x) { return 1.0f - 2.0f / (__expf(2.0f * x) + 1.0f); }
static __device__ __forceinline__ unsigned short f2b(float v) {
    __hip_bfloat16 h = __float2bfloat16(v);
    return *reinterpret_cast<unsigned short*>(&h);
}
static __device__ __forceinline__ short8 ld16(const unsigned short* p) {
    return *reinterpret_cast<const short8*>(p);
}

// ---------------- zero-init h buffer 0 and flag block ----------------
__global__ void k_init(unsigned short* __restrict__ hb0, int* __restrict__ flags) {
    int i = blockIdx.x * 256 + threadIdx.x;
    if (i < BB * HH) hb0[i] = 0;
    if (i < 16384) flags[i] = 0;   // 256 leaf slots + 4 go slots, 128B-strided
}

// ---------------- Wh -> bf16, transposed, gate-interleaved ----------------
__global__ void k_conv_wh(const float* __restrict__ Wfh, const float* __restrict__ Wih,
                          const float* __restrict__ Wgh, const float* __restrict__ Woh,
                          unsigned short* __restrict__ WhT) {
    __shared__ float t[32][33];
    int g = blockIdx.z;
    const float* W = (g == 0) ? Wfh : (g == 1) ? Wih : (g == 2) ? Wgh : Woh;
    int h0 = blockIdx.x * 32, k0 = blockIdx.y * 32;
    int tx = threadIdx.x & 31, ty = threadIdx.x >> 5;
    for (int r = 0; r < 4; r++) {
        int k = ty + r * 8;
        t[k][tx] = W[(size_t)(k0 + k) * HH + h0 + tx];
    }
    __syncthreads();
    for (int r = 0; r < 4; r++) {
        int hl = ty + r * 8;
        int j  = (h0 + hl) * 4 + g;
        WhT[(size_t)j * HH + k0 + tx] = f2b(t[tx][hl]);
    }
}

// ---------------- proj[c][j] = emb[c,:] @ Wx[:,hcol] + b ----------------
__global__ void k_proj(const float* __restrict__ emb,
                       const float* __restrict__ Wfx, const float* __restrict__ Wix,
                       const float* __restrict__ Wgx, const float* __restrict__ Wox,
                       const float* __restrict__ bf_, const float* __restrict__ bi_,
                       const float* __restrict__ bg_, const float* __restrict__ bo_,
                       float* __restrict__ proj) {
    int c = blockIdx.y;
    int j = blockIdx.x * 256 + threadIdx.x;
    int hcol = j >> 2, g = j & 3;
    const float* Wx = (g == 0) ? Wfx : (g == 1) ? Wix : (g == 2) ? Wgx : Wox;
    const float* bb = (g == 0) ? bf_ : (g == 1) ? bi_ : (g == 2) ? bg_ : bo_;
    float acc = bb[hcol];
    const float* er = emb + (size_t)c * DD;
    for (int d = 0; d < DD; d++) acc += er[d] * Wx[(size_t)d * HH + hcol];
    proj[(size_t)c * G4 + j] = acc;
}

// ---- L2-bypassing 16B load from rolling base (h is cross-XCD dynamic data)
#define LDAB(d, B, L) asm volatile("global_load_dwordx4 %0, %1, off offset:" L " sc0 sc1" \
                                   : "=v"(d) : "v"(B))
// 4 contiguous 1KB loads then advance base 4KB (13-bit offset limit)
#define LD4(A, I) do { \
    LDAB(A[(I)+0], p, "0"); LDAB(A[(I)+1], p, "1024"); \
    LDAB(A[(I)+2], p, "2048"); LDAB(A[(I)+3], p, "3072"); p += 4096; } while (0)
#define LD16(A) do { LD4(A,0); LD4(A,4); LD4(A,8); LD4(A,12); } while (0)

// ---- waitcnt with data-tie so MFMAs can't be scheduled before the wait
#define WAITA(N, A) asm volatile("s_waitcnt vmcnt(" N ")" : \
    "+v"(A[0]),"+v"(A[1]),"+v"(A[2]),"+v"(A[3]),"+v"(A[4]),"+v"(A[5]),"+v"(A[6]),"+v"(A[7]), \
    "+v"(A[8]),"+v"(A[9]),"+v"(A[10]),"+v"(A[11]),"+v"(A[12]),"+v"(A[13]),"+v"(A[14]),"+v"(A[15]))

#define MF16(A, KB) do { \
    acc0 = __builtin_amdgcn_mfma_f32_32x32x16_bf16(A[0],  breg[(KB)+0],  acc0, 0,0,0); \
    acc1 = __builtin_amdgcn_mfma_f32_32x32x16_bf16(A[1],  breg[(KB)+1],  acc1, 0,0,0); \
    acc0 = __builtin_amdgcn_mfma_f32_32x32x16_bf16(A[2],  breg[(KB)+2],  acc0, 0,0,0); \
    acc1 = __builtin_amdgcn_mfma_f32_32x32x16_bf16(A[3],  breg[(KB)+3],  acc1, 0,0,0); \
    acc0 = __builtin_amdgcn_mfma_f32_32x32x16_bf16(A[4],  breg[(KB)+4],  acc0, 0,0,0); \
    acc1 = __builtin_amdgcn_mfma_f32_32x32x16_bf16(A[5],  breg[(KB)+5],  acc1, 0,0,0); \
    acc0 = __builtin_amdgcn_mfma_f32_32x32x16_bf16(A[6],  breg[(KB)+6],  acc0, 0,0,0); \
    acc1 = __builtin_amdgcn_mfma_f32_32x32x16_bf16(A[7],  breg[(KB)+7],  acc1, 0,0,0); \
    acc0 = __builtin_amdgcn_mfma_f32_32x32x16_bf16(A[8],  breg[(KB)+8],  acc0, 0,0,0); \
    acc1 = __builtin_amdgcn_mfma_f32_32x32x16_bf16(A[9],  breg[(KB)+9],  acc1, 0,0,0); \
    acc0 = __builtin_amdgcn_mfma_f32_32x32x16_bf16(A[10], breg[(KB)+10], acc0, 0,0,0); \
    acc1 = __builtin_amdgcn_mfma_f32_32x32x16_bf16(A[11], breg[(KB)+11], acc1, 0,0,0); \
    acc0 = __builtin_amdgcn_mfma_f32_32x32x16_bf16(A[12], breg[(KB)+12], acc0, 0,0,0); \
    acc1 = __builtin_amdgcn_mfma_f32_32x32x16_bf16(A[13], breg[(KB)+13], acc1, 0,0,0); \
    acc0 = __builtin_amdgcn_mfma_f32_32x32x16_bf16(A[14], breg[(KB)+14], acc0, 0,0,0); \
    acc1 = __builtin_amdgcn_mfma_f32_32x32x16_bf16(A[15], breg[(KB)+15], acc1, 0,0,0); \
} while (0)

// 16 gathered proj loads (normal caching), completed by the poll's vmcnt(0)
#define PRLOAD(DSTA, CLSBUF) do { \
    _Pragma("unroll") \
    for (int r = 0; r < 16; r++) { \
        int row = (r & 3) + 8 * (r >> 2) + 4 * half; \
        const float* pa = proj + (size_t)CLSBUF[row] * G4 + jg; \
        asm volatile("global_load_dword %0, %1, off" : "=v"(DSTA[r]) \
                     : "v"((unsigned long long)pa)); \
    } \
} while (0)

// ---------------- persistent LSTM scan ----------------
// 256 WGs x 128 thr (2 waves). WG(mg = wg&3, ng = wg>>2): rows mg*32..+32,
// gate-cols ng*64..+64. WhT slice in registers (full K).
// h stored FRAGMENT-MAJOR: hF[mg][kk][lane][8bf16] so A-loads are 64 x 1KB
// fully-contiguous sector-perfect streams (lane l: m = l&31, k = kk*16+(l>>5)*8+j).
// Sync per mg-group: leaves post flags[wg]; aggregator wave (WG mg<4, wave 0)
// polls its 64 leaves, posts go[mg]; everyone else polls go[mg] with a single
// lane-uniform load (1 cacheline/wave/iter -> no L3 request congestion).
__global__ __launch_bounds__(128, 1)
void k_scan(const int* __restrict__ x, const float* __restrict__ proj,
            const unsigned short* __restrict__ WhT,
            unsigned short* __restrict__ hb0, unsigned short* __restrict__ hb1,
            float* __restrict__ hf32, int* __restrict__ flags) {
    const int wg = blockIdx.x, tid = threadIdx.x;
    const int lane = tid & 63, wv = tid >> 6;
    const int l31 = lane & 31, half = lane >> 5;
    const int mg = wg & 3, ng = wg >> 2;
    const int m0 = mg * 32, n0 = ng * 64;
    const int jg = n0 + wv * 32 + l31;       // this lane's gate-col

    // B fragments: WhT[jg][k], k = kk*16 + half*8 + j  (256 regs)
    short8 breg[64];
    {
        const unsigned short* Bp = WhT + (size_t)jg * HH + half * 8;
        #pragma unroll
        for (int kk = 0; kk < 64; kk++) breg[kk] = ld16(Bp + kk * 16);
    }

    __shared__ float sg[32][68];    // sigmoided gates [row][gate-col]
    __shared__ int   clsS[2][32];   // double-buffered class ids

    float Cst[4] = {0.0f, 0.0f, 0.0f, 0.0f};
    const int urow = tid & 31, uq = tid >> 5;

    if (tid < 32) clsS[0][tid] = x[(size_t)(m0 + tid) * SS];
    __syncthreads();

    // fragment-major bases: hF byte offset = mg*65536 + kk*1024 + lane*16
    const unsigned long long ab0 =
        (unsigned long long)((char*)hb0 + mg * 65536 + lane * 16);
    const unsigned long long ab1 =
        (unsigned long long)((char*)hb1 + mg * 65536 + lane * 16);
    // producer store base: cell = urow + 32*(uq>>1), sub = (uq&1)*8 bytes
    const unsigned long long sb0 = (unsigned long long)((char*)hb0 + mg * 65536
        + ng * 1024 + (urow + ((uq >> 1) << 5)) * 16 + (uq & 1) * 8);
    const unsigned long long sb1 = (unsigned long long)((char*)hb1 + mg * 65536
        + ng * 1024 + (urow + ((uq >> 1) << 5)) * 16 + (uq & 1) * 8);

    const unsigned long long postAddr = (unsigned long long)(flags + (size_t)wg * 32);
    const unsigned long long leafAddr =
        (unsigned long long)(flags + ((size_t)(lane << 2) + mg) * 32);
    const unsigned long long goAddr =
        (unsigned long long)(flags + (size_t)(8192 + mg * 32));
    const bool isAggWave = (ng == 0) && (wv == 0);

    float pr[16];
    PRLOAD(pr, clsS[0]);            // step-0 proj gather (drained by first WAITA)

    for (int s = 0; s < SS; s++) {
        const int cur = s & 1;
        unsigned long long p = cur ? ab1 : ab0;
        const unsigned long long sb = cur ? sb0 : sb1;   // store to the OTHER buffer

        // ---- pipelined A loads: 4 groups x 16 x 1KB contiguous ----
        short8 a0[16], a1[16], a2[16], a3[16];
        LD16(a0);
        LD16(a1);

        f32x16 acc0, acc1;
        #pragma unroll
        for (int r = 0; r < 16; r++) { acc0[r] = 0.0f; acc1[r] = 0.0f; }

        WAITA("16", a0);
        LD16(a2);
        MF16(a0, 0);
        WAITA("16", a1);
        LD16(a3);
        MF16(a1, 16);
        WAITA("16", a2);
        MF16(a2, 32);
        WAITA("0", a3);
        MF16(a3, 48);

        // ---- epilogue: add preloaded proj, sigmoid, stash in LDS ----
        // C/D layout (m74/m101): col = lane&31, row = (r&3) + 8*(r>>2) + 4*(lane>>5)
        #pragma unroll
        for (int r = 0; r < 16; r++) {
            int row = (r & 3) + 8 * (r >> 2) + 4 * half;
            sg[row][wv * 32 + l31] = sigm(acc0[r] + acc1[r] + pr[r]);
        }
        __syncthreads();

        // ---- pointwise: thread owns (row = tid&31, hcols uq*4..+4) ----
        {
            const float rr = (clsS[cur][urow] > 0) ? 1.0f : 0.0f;
            unsigned short hv[4];
            #pragma unroll
            for (int q = 0; q < 4; q++) {
                float4 gq = *reinterpret_cast<const float4*>(&sg[urow][uq * 16 + q * 4]);
                float cn = (gq.z * gq.y + Cst[q] * gq.x) * rr;   // (g*i + C*f)*r
                Cst[q] = cn;
                float hvv = gq.w * tanh_(cn);
                hv[q] = f2b(hvv);
                if (s == SS - 1)
                    hf32[(size_t)(m0 + urow) * HH + ng * 16 + uq * 4 + q] = hvv;
            }
            unsigned long long pk = (unsigned long long)hv[0]
                                  | ((unsigned long long)hv[1] << 16)
                                  | ((unsigned long long)hv[2] << 32)
                                  | ((unsigned long long)hv[3] << 48);
            asm volatile("global_store_dwordx2 %0, %1, off sc0 sc1" :: "v"(sb), "v"(pk) : "memory");
            if (s + 1 < SS && tid < 32)
                clsS[cur ^ 1][tid] = x[(size_t)(m0 + tid) * SS + s + 1];
        }

        // ---- barrier: leaves -> aggregator wave -> go word ----
        if (s < SS - 1) {
            asm volatile("s_waitcnt vmcnt(0)" ::: "memory");   // h-store drained at L3
            __syncthreads();
            if (tid == 0) {
                int fv = s + 1;
                asm volatile("global_store_dword %0, %1, off sc0 sc1"
                             :: "v"(postAddr), "v"(fv) : "memory");
            }
            PRLOAD(pr, clsS[cur ^ 1]);     // next step's proj gather, rides the poll
            if (isAggWave) {
                int got;
                do {
                    asm volatile("global_load_dword %0, %1, off sc0 sc1\n\t"
                                 "s_waitcnt vmcnt(0)"
                                 : "=v"(got) : "v"(leafAddr) : "memory");
                } while (__ballot(got >= s + 1) != ~0ull);
                if (tid == 0) {
                    int fv = s + 1;
                    asm volatile("global_store_dword %0, %1, off sc0 sc1"
                                 :: "v"(goAddr), "v"(fv) : "memory");
                }
            } else {
                int got;
                do {   // lane-uniform single-line poll
                    asm volatile("global_load_dword %0, %1, off sc0 sc1\n\t"
                                 "s_waitcnt vmcnt(0)"
                                 : "=v"(got) : "v"(goAddr) : "memory");
                } while (got < s + 1);
            }
        }
    }
}

// ---------------- final projection + log_softmax ----------------
__global__ void k_final(const float* __restrict__ hf32, const float* __restrict__ Wph,
                        const float* __restrict__ bp, float* __restrict__ out) {
    __shared__ float red[128];
    int b = blockIdx.x, c = threadIdx.x;
    const float* hr = hf32 + (size_t)b * HH;
    float acc = bp[c];
    for (int k = 0; k < HH; k++) acc += hr[k] * Wph[(size_t)k * NCC + c];
    red[c] = acc;
    __syncthreads();
    for (int st = 64; st > 0; st >>= 1) {
        if (c < st) red[c] = fmaxf(red[c], red[c + st]);
        __syncthreads();
    }
    float m = red[0];
    __syncthreads();
    red[c] = __expf(acc - m);
    __syncthreads();
    for (int st = 64; st > 0; st >>= 1) {
        if (c < st) red[c] += red[c + st];
        __syncthreads();
    }
    out[(size_t)b * NCC + c] = acc - m - __logf(red[0]);
}

extern "C" void kernel_launch(void* const* d_in, const int* in_sizes, int n_in,
                              void* d_out, int out_size, void* d_ws, size_t ws_size,
                              hipStream_t stream) {
    const int*   x   = (const int*)  d_in[0];
    const float* emb = (const float*)d_in[1];
    const float* Wfx = (const float*)d_in[2];
    const float* Wfh = (const float*)d_in[3];
    const float* bf_ = (const float*)d_in[4];
    const float* Wix = (const float*)d_in[5];
    const float* Wih = (const float*)d_in[6];
    const float* bi_ = (const float*)d_in[7];
    const float* Wgx = (const float*)d_in[8];
    const float* Wgh = (const float*)d_in[9];
    const float* bg_ = (const float*)d_in[10];
    const float* Wox = (const float*)d_in[11];
    const float* Woh = (const float*)d_in[12];
    const float* bo_ = (const float*)d_in[13];
    const float* Wph = (const float*)d_in[14];
    const float* bp_ = (const float*)d_in[15];
    float* out = (float*)d_out;

    char* ws = (char*)d_ws;
    unsigned short* WhT   = (unsigned short*)(ws);              // 8 MB
    float*          proj  = (float*)(ws + 8388608);             // 2.02 MB -> ends 10502144
    int*            flags = (int*)(ws + 10502656);              // 64 KB (16384 ints)
    unsigned short* hb0   = (unsigned short*)(ws + 10568192);   // 256 KB
    unsigned short* hb1   = (unsigned short*)(ws + 10830336);   // 256 KB
    float*          hf32  = (float*)(ws + 11092480);            // 512 KB -> ends ~11.6 MB

    k_init<<<dim3(512), dim3(256), 0, stream>>>(hb0, flags);
    k_conv_wh<<<dim3(32, 32, 4), dim3(256), 0, stream>>>(Wfh, Wih, Wgh, Woh, WhT);
    k_proj<<<dim3(16, NCLS), dim3(256), 0, stream>>>(emb, Wfx, Wix, Wgx, Wox,
                                                     bf_, bi_, bg_, bo_, proj);
    k_scan<<<dim3(NWG), dim3(128), 0, stream>>>(x, proj, WhT, hb0, hb1, hf32, flags);
    k_final<<<dim3(128), dim3(128), 0, stream>>>(hf32, Wph, bp_, out);
}